// Round 2
// baseline (131.366 us; speedup 1.0000x reference)
//
#include <hip/hip_runtime.h>
#include <math.h>

// AnnealingTopKSoftMax: per-row top-8 mask + softmax over 512-wide rows.
// One wave (64 lanes) per row. Split-row ownership for dense transactions:
// lane l owns elements [4l, 4l+4) (j=0..3) and [256+4l, 256+4l+4) (j=4..7),
// so every global load/store is 16B/lane at 16B stride (fully dense).
//
// Tie-break must equal jax.lax.top_k (lowest global index):
//   - within lane: strict '>' scan keeps lowest j; j order == global idx order.
//   - across lanes: any first-half (j<4, idx<256) candidate beats any
//     second-half candidate; within a half, lower lane == lower idx.
//     => two ballots: prefer ballot(cand && j<4), else ballot(cand).

#define DEPTH 512

__global__ __launch_bounds__(256, 8)
void AnnealingTopKSoftMax_kernel(const float* __restrict__ in,
                                 float* __restrict__ out) {
    const int wave = threadIdx.x >> 6;       // 0..3
    const int lane = threadIdx.x & 63;
    const int row  = (blockIdx.x << 2) | wave;

    const size_t base = (size_t)row * DEPTH;
    const float4 a = *reinterpret_cast<const float4*>(in + base + lane * 4);
    const float4 b = *reinterpret_cast<const float4*>(in + base + 256 + lane * 4);
    float x[8] = {a.x, a.y, a.z, a.w, b.x, b.y, b.z, b.w};

    unsigned rem = 0xFFu;   // unconsumed local elements
    unsigned sel = 0u;      // selected (top-8) local elements

    // initial local best; strict '>' keeps lowest j on ties
    float bv = x[0];
    int   bj = 0;
#pragma unroll
    for (int j = 1; j < 8; ++j) {
        if (x[j] > bv) { bv = x[j]; bj = j; }
    }

    float M = 0.0f, S = 1.0f;

#pragma unroll
    for (int r = 0; r < 8; ++r) {
        // wave-wide max of per-lane bests
        float v = bv;
#pragma unroll
        for (int off = 32; off; off >>= 1)
            v = fmaxf(v, __shfl_xor(v, off, 64));

        if (r == 0) {
            M = v;                       // row max; exp(M-M)=1 folded into S init
        } else {
            S += __expf(v - M);
        }

        // winner lane = lowest global index among candidates
        const bool cand = (bv == v);
        const unsigned long long blo = __ballot(cand && (bj < 4));
        const unsigned long long bhi = __ballot(cand);
        const int L = (blo ? __ffsll(blo) : __ffsll(bhi)) - 1;
        const bool win = (lane == L);

        const unsigned bit = (win ? 1u : 0u) << bj;
        sel |= bit;
        rem &= ~bit;

        if (r < 7) {   // rescan remaining (uniform, branchless)
            float nb = -INFINITY;
            int   nj = 0;
#pragma unroll
            for (int j = 0; j < 8; ++j) {
                const float xv = ((rem >> j) & 1u) ? x[j] : -INFINITY;
                if (xv > nb) { nb = xv; nj = j; }
            }
            bv = nb; bj = nj;
        }
    }

    const float inv = 1.0f / S;
    float o[8];
#pragma unroll
    for (int j = 0; j < 8; ++j) {
        const float ej = __expf(x[j] - M) * inv;
        o[j] = ((sel >> j) & 1u) ? ej : 0.0f;
    }

    *reinterpret_cast<float4*>(out + base + lane * 4) =
        make_float4(o[0], o[1], o[2], o[3]);
    *reinterpret_cast<float4*>(out + base + 256 + lane * 4) =
        make_float4(o[4], o[5], o[6], o[7]);
}

extern "C" void kernel_launch(void* const* d_in, const int* in_sizes, int n_in,
                              void* d_out, int out_size, void* d_ws, size_t ws_size,
                              hipStream_t stream) {
    const float* in = (const float*)d_in[0];
    float* out = (float*)d_out;
    const int rows = in_sizes[0] / DEPTH;      // 131072
    const int blocks = rows / 4;               // 4 waves (rows) per block
    AnnealingTopKSoftMax_kernel<<<blocks, 256, 0, stream>>>(in, out);
}

// Round 3
// 119.491 us; speedup vs baseline: 1.0994x; 1.0994x over previous
//
#include <hip/hip_runtime.h>
#include <math.h>

// AnnealingTopKSoftMax: per-row top-8 mask + softmax over 512-wide rows.
// One wave (64 lanes) per row; lane l owns elements [8l, 8l+8) (R1 layout:
// lane-major order == global index order, wave footprint contiguous 2KB).
//
// Selection: bitonic top-8 butterfly.
//  - lane-local sort of its 8 values, descending (Batcher, 19 comparators)
//  - 6 x shfl_xor steps; merge two sorted-8 lists into top-8:
//      t[i] = max(v[i], w[7-i])   (top-8 multiset, bitonic)
//      then 12-comparator bitonic merge -> sorted desc
//  - after 6 steps all lanes hold the row's top-8 sorted desc.
// M = v[0], T = v[7] (8th largest), S = sum exp(v[i]-M) computed in-lane.
// Mask: x > T strictly, plus lowest-global-index tie fill for values == T
// (exactly matches jax.lax.top_k index tie-break semantics).

#define DEPTH 512

typedef float f32x4 __attribute__((ext_vector_type(4)));

#define CE(arr, i, j)                         \
    do {                                      \
        float _hi = fmaxf(arr[i], arr[j]);    \
        float _lo = fminf(arr[i], arr[j]);    \
        arr[i] = _hi;                         \
        arr[j] = _lo;                         \
    } while (0)

__global__ __launch_bounds__(256, 8)
void AnnealingTopKSoftMax_kernel(const float* __restrict__ in,
                                 float* __restrict__ out) {
    const int wave = threadIdx.x >> 6;       // 0..3
    const int lane = threadIdx.x & 63;
    const int row  = (blockIdx.x << 2) | wave;

    const size_t base = (size_t)row * DEPTH + (size_t)lane * 8;
    const f32x4* p = reinterpret_cast<const f32x4*>(in + base);
    const f32x4 a = __builtin_nontemporal_load(p);
    const f32x4 b = __builtin_nontemporal_load(p + 1);
    float x[8] = {a[0], a[1], a[2], a[3], b[0], b[1], b[2], b[3]};

    // ---- lane-local descending sort (Batcher odd-even mergesort, 19 CE) ----
    float v[8] = {x[0], x[1], x[2], x[3], x[4], x[5], x[6], x[7]};
    CE(v, 0, 1); CE(v, 2, 3); CE(v, 4, 5); CE(v, 6, 7);
    CE(v, 0, 2); CE(v, 1, 3); CE(v, 4, 6); CE(v, 5, 7);
    CE(v, 1, 2); CE(v, 5, 6);
    CE(v, 0, 4); CE(v, 1, 5); CE(v, 2, 6); CE(v, 3, 7);
    CE(v, 2, 4); CE(v, 3, 5);
    CE(v, 1, 2); CE(v, 3, 4); CE(v, 5, 6);

    // ---- butterfly: merge sorted-8 lists across lanes, keep top-8 ----
#pragma unroll
    for (int off = 1; off <= 32; off <<= 1) {
        float w[8];
#pragma unroll
        for (int i = 0; i < 8; ++i) w[i] = __shfl_xor(v[i], off, 64);
        float t[8];
#pragma unroll
        for (int i = 0; i < 8; ++i) t[i] = fmaxf(v[i], w[7 - i]);
        // bitonic merge (desc), distances 4,2,1
        CE(t, 0, 4); CE(t, 1, 5); CE(t, 2, 6); CE(t, 3, 7);
        CE(t, 0, 2); CE(t, 1, 3); CE(t, 4, 6); CE(t, 5, 7);
        CE(t, 0, 1); CE(t, 2, 3); CE(t, 4, 5); CE(t, 6, 7);
#pragma unroll
        for (int i = 0; i < 8; ++i) v[i] = t[i];
    }

    // all lanes now hold identical row top-8, sorted descending
    const float M = v[0];
    const float T = v[7];

    float S = 1.0f;   // exp(v[0]-M) = 1
#pragma unroll
    for (int i = 1; i < 8; ++i) S += __expf(v[i] - M);

    // count of top-8 values strictly greater than T (wave-uniform)
    int cnt_gt = 0;
#pragma unroll
    for (int i = 0; i < 8; ++i) cnt_gt += (v[i] > T) ? 1 : 0;
    const int need = 8 - cnt_gt;   // how many ==T elements to select (>=1)

    // per-lane masks
    unsigned selmask = 0u, eqmask = 0u;
#pragma unroll
    for (int j = 0; j < 8; ++j) {
        selmask |= (x[j] > T ? 1u : 0u) << j;
        eqmask  |= (x[j] == T ? 1u : 0u) << j;
    }

    // tie fill: pick `need` elements == T at lowest global index
    // (lane-major layout => lowest lane, then lowest j). need is wave-uniform.
    for (int t = 0; t < need; ++t) {
        const unsigned long long ball = __ballot(eqmask != 0u);
        const int L = __ffsll(ball) - 1;
        if (lane == L) {
            const int j = __ffs(eqmask) - 1;
            selmask |= 1u << j;
            eqmask &= eqmask - 1u;
        }
    }

    const float inv = 1.0f / S;
    f32x4 o0, o1;
#pragma unroll
    for (int j = 0; j < 8; ++j) {
        const float ej = __expf(x[j] - M) * inv;
        const float oj = ((selmask >> j) & 1u) ? ej : 0.0f;
        if (j < 4) o0[j] = oj; else o1[j - 4] = oj;
    }

    f32x4* q = reinterpret_cast<f32x4*>(out + base);
    __builtin_nontemporal_store(o0, q);
    __builtin_nontemporal_store(o1, q + 1);
}

extern "C" void kernel_launch(void* const* d_in, const int* in_sizes, int n_in,
                              void* d_out, int out_size, void* d_ws, size_t ws_size,
                              hipStream_t stream) {
    const float* in = (const float*)d_in[0];
    float* out = (float*)d_out;
    const int rows = in_sizes[0] / DEPTH;      // 131072
    const int blocks = rows / 4;               // 4 waves (rows) per block
    AnnealingTopKSoftMax_kernel<<<blocks, 256, 0, stream>>>(in, out);
}

// Round 5
// 102.787 us; speedup vs baseline: 1.2780x; 1.1625x over previous
//
#include <hip/hip_runtime.h>
#include <math.h>

// AnnealingTopKSoftMax: per-row top-8 mask + softmax over 512-wide rows.
// One wave (64 lanes) per row; lane l owns elements [8l, 8l+8) (lane-major,
// wave footprint per load instruction = contiguous 2KB).
//
// Selection strategy (zero DS-pipe instructions):
//  - lane-local descending sort of the 8 owned values (Batcher, 19 CE)
//  - 8 rounds of: wave-wide max via DPP tree (row_shr 1/2/4/8 +
//    row_bcast15/31 + readlane 63) -> ballot -> lowest winning lane shifts
//    its sorted list down by one. Extracts the exact top-8 multiset.
//  - M = 1st extracted, T = 8th extracted, S = sum exp(sv_r - M).
//  - output mask: x > T strictly, plus lowest-global-index tie fill for
//    values == T (exact jax.lax.top_k tie-break; proven in R3).

#define DEPTH 512

typedef float f32x4 __attribute__((ext_vector_type(4)));

#define CE(arr, i, j)                         \
    do {                                      \
        float _hi = fmaxf(arr[i], arr[j]);    \
        float _lo = fminf(arr[i], arr[j]);    \
        arr[i] = _hi;                         \
        arr[j] = _lo;                         \
    } while (0)

template <int CTRL>
__device__ __forceinline__ float dpp_max_step(float v) {
    int vi = __float_as_int(v);
    // old = vi, bound_ctrl = false: OOB/disabled source lanes keep own value
    int sh = __builtin_amdgcn_update_dpp(vi, vi, CTRL, 0xF, 0xF, false);
    return fmaxf(v, __int_as_float(sh));
}

// wave-wide max of 64 lanes, returned as wave-uniform scalar
__device__ __forceinline__ float wave_max64(float v) {
    v = dpp_max_step<0x111>(v);  // row_shr:1
    v = dpp_max_step<0x112>(v);  // row_shr:2
    v = dpp_max_step<0x114>(v);  // row_shr:4
    v = dpp_max_step<0x118>(v);  // row_shr:8  -> lane15/31/47/63 = row max
    v = dpp_max_step<0x142>(v);  // row_bcast:15
    v = dpp_max_step<0x143>(v);  // row_bcast:31 -> lane63 = full max
    return __int_as_float(__builtin_amdgcn_readlane(__float_as_int(v), 63));
}

__global__ __launch_bounds__(256, 8)
void AnnealingTopKSoftMax_kernel(const float* __restrict__ in,
                                 float* __restrict__ out) {
    const int wave = threadIdx.x >> 6;
    const int lane = threadIdx.x & 63;
    const int row  = (blockIdx.x << 2) | wave;

    const size_t base = (size_t)row * DEPTH + (size_t)lane * 8;
    const f32x4* p = reinterpret_cast<const f32x4*>(in + base);
    const f32x4 a = __builtin_nontemporal_load(p);
    const f32x4 b = __builtin_nontemporal_load(p + 1);
    const float x[8] = {a[0], a[1], a[2], a[3], b[0], b[1], b[2], b[3]};

    // ---- lane-local descending sort (values only; 19 CE) ----
    float v[8] = {x[0], x[1], x[2], x[3], x[4], x[5], x[6], x[7]};
    CE(v, 0, 1); CE(v, 2, 3); CE(v, 4, 5); CE(v, 6, 7);
    CE(v, 0, 2); CE(v, 1, 3); CE(v, 4, 6); CE(v, 5, 7);
    CE(v, 1, 2); CE(v, 5, 6);
    CE(v, 0, 4); CE(v, 1, 5); CE(v, 2, 6); CE(v, 3, 7);
    CE(v, 2, 4); CE(v, 3, 5);
    CE(v, 1, 2); CE(v, 3, 4); CE(v, 5, 6);

    // ---- 8 extraction rounds: DPP wave max + winner shifts sorted list ----
    float sv[8];
    float M = 0.0f, S = 1.0f;
#pragma unroll
    for (int r = 0; r < 8; ++r) {
        const float m = wave_max64(v[0]);
        sv[r] = m;
        if (r == 0) M = m;
        else        S += __expf(m - M);

        if (r < 7) {
            const unsigned long long ball = __ballot(v[0] == m);
            const int L = __ffsll(ball) - 1;
            const bool win = (lane == L);
            v[0] = win ? v[1] : v[0];
            v[1] = win ? v[2] : v[1];
            v[2] = win ? v[3] : v[2];
            v[3] = win ? v[4] : v[3];
            v[4] = win ? v[5] : v[4];
            v[5] = win ? v[6] : v[5];
            v[6] = win ? v[7] : v[6];
            v[7] = win ? -INFINITY : v[7];
        }
    }

    const float T = sv[7];   // 8th largest (wave-uniform)

    // how many ==T elements belong in the top-8 (multiset count, uniform)
    int need = 1;
#pragma unroll
    for (int r = 0; r < 7; ++r) need += (sv[r] == T) ? 1 : 0;

    // per-lane masks over original positions
    unsigned selmask = 0u, eqmask = 0u;
#pragma unroll
    for (int j = 0; j < 8; ++j) {
        selmask |= (x[j] > T ? 1u : 0u) << j;
        eqmask  |= (x[j] == T ? 1u : 0u) << j;
    }

    // tie fill: `need` elements == T at lowest global index
    for (int t = 0; t < need; ++t) {
        const unsigned long long ball = __ballot(eqmask != 0u);
        const int L = __ffsll(ball) - 1;
        if (lane == L) {
            const int j = __ffs(eqmask) - 1;
            selmask |= 1u << j;
            eqmask &= eqmask - 1u;
        }
    }

    const float inv = 1.0f / S;
    f32x4 o0, o1;
#pragma unroll
    for (int j = 0; j < 8; ++j) {
        const float ej = __expf(x[j] - M) * inv;
        const float oj = ((selmask >> j) & 1u) ? ej : 0.0f;
        if (j < 4) o0[j] = oj; else o1[j - 4] = oj;
    }

    f32x4* q = reinterpret_cast<f32x4*>(out + base);
    __builtin_nontemporal_store(o0, q);
    __builtin_nontemporal_store(o1, q + 1);
}

extern "C" void kernel_launch(void* const* d_in, const int* in_sizes, int n_in,
                              void* d_out, int out_size, void* d_ws, size_t ws_size,
                              hipStream_t stream) {
    const float* in = (const float*)d_in[0];
    float* out = (float*)d_out;
    const int rows = in_sizes[0] / DEPTH;      // 131072
    const int blocks = rows / 4;               // 4 waves (rows) per block
    AnnealingTopKSoftMax_kernel<<<blocks, 256, 0, stream>>>(in, out);
}

// Round 6
// 86.932 us; speedup vs baseline: 1.5111x; 1.1824x over previous
//
#include <hip/hip_runtime.h>
#include <math.h>

// AnnealingTopKSoftMax: per-row top-8 mask + softmax over 512-wide rows.
// One wave (64 lanes) per row; lane l owns elements [8l, 8l+8).
// R6 = R5 with ONE change: input loads are plain (cached) instead of
// nontemporal; stores remain nontemporal. Isolates the NT-load effect.

#define DEPTH 512

typedef float f32x4 __attribute__((ext_vector_type(4)));

#define CE(arr, i, j)                         \
    do {                                      \
        float _hi = fmaxf(arr[i], arr[j]);    \
        float _lo = fminf(arr[i], arr[j]);    \
        arr[i] = _hi;                         \
        arr[j] = _lo;                         \
    } while (0)

template <int CTRL>
__device__ __forceinline__ float dpp_max_step(float v) {
    int vi = __float_as_int(v);
    // old = vi, bound_ctrl = false: OOB/disabled source lanes keep own value
    int sh = __builtin_amdgcn_update_dpp(vi, vi, CTRL, 0xF, 0xF, false);
    return fmaxf(v, __int_as_float(sh));
}

// wave-wide max of 64 lanes, returned as wave-uniform scalar
__device__ __forceinline__ float wave_max64(float v) {
    v = dpp_max_step<0x111>(v);  // row_shr:1
    v = dpp_max_step<0x112>(v);  // row_shr:2
    v = dpp_max_step<0x114>(v);  // row_shr:4
    v = dpp_max_step<0x118>(v);  // row_shr:8  -> lane15/31/47/63 = row max
    v = dpp_max_step<0x142>(v);  // row_bcast:15
    v = dpp_max_step<0x143>(v);  // row_bcast:31 -> lane63 = full max
    return __int_as_float(__builtin_amdgcn_readlane(__float_as_int(v), 63));
}

__global__ __launch_bounds__(256, 8)
void AnnealingTopKSoftMax_kernel(const float* __restrict__ in,
                                 float* __restrict__ out) {
    const int wave = threadIdx.x >> 6;
    const int lane = threadIdx.x & 63;
    const int row  = (blockIdx.x << 2) | wave;

    const size_t base = (size_t)row * DEPTH + (size_t)lane * 8;
    const f32x4* p = reinterpret_cast<const f32x4*>(in + base);
    const f32x4 a = p[0];          // plain cached load (A/B vs R5's NT load)
    const f32x4 b = p[1];
    const float x[8] = {a[0], a[1], a[2], a[3], b[0], b[1], b[2], b[3]};

    // ---- lane-local descending sort (values only; 19 CE) ----
    float v[8] = {x[0], x[1], x[2], x[3], x[4], x[5], x[6], x[7]};
    CE(v, 0, 1); CE(v, 2, 3); CE(v, 4, 5); CE(v, 6, 7);
    CE(v, 0, 2); CE(v, 1, 3); CE(v, 4, 6); CE(v, 5, 7);
    CE(v, 1, 2); CE(v, 5, 6);
    CE(v, 0, 4); CE(v, 1, 5); CE(v, 2, 6); CE(v, 3, 7);
    CE(v, 2, 4); CE(v, 3, 5);
    CE(v, 1, 2); CE(v, 3, 4); CE(v, 5, 6);

    // ---- 8 extraction rounds: DPP wave max + winner shifts sorted list ----
    float sv[8];
    float M = 0.0f, S = 1.0f;
#pragma unroll
    for (int r = 0; r < 8; ++r) {
        const float m = wave_max64(v[0]);
        sv[r] = m;
        if (r == 0) M = m;
        else        S += __expf(m - M);

        if (r < 7) {
            const unsigned long long ball = __ballot(v[0] == m);
            const int L = __ffsll(ball) - 1;
            const bool win = (lane == L);
            v[0] = win ? v[1] : v[0];
            v[1] = win ? v[2] : v[1];
            v[2] = win ? v[3] : v[2];
            v[3] = win ? v[4] : v[3];
            v[4] = win ? v[5] : v[4];
            v[5] = win ? v[6] : v[5];
            v[6] = win ? v[7] : v[6];
            v[7] = win ? -INFINITY : v[7];
        }
    }

    const float T = sv[7];   // 8th largest (wave-uniform)

    // how many ==T elements belong in the top-8 (multiset count, uniform)
    int need = 1;
#pragma unroll
    for (int r = 0; r < 7; ++r) need += (sv[r] == T) ? 1 : 0;

    // per-lane masks over original positions
    unsigned selmask = 0u, eqmask = 0u;
#pragma unroll
    for (int j = 0; j < 8; ++j) {
        selmask |= (x[j] > T ? 1u : 0u) << j;
        eqmask  |= (x[j] == T ? 1u : 0u) << j;
    }

    // tie fill: `need` elements == T at lowest global index
    for (int t = 0; t < need; ++t) {
        const unsigned long long ball = __ballot(eqmask != 0u);
        const int L = __ffsll(ball) - 1;
        if (lane == L) {
            const int j = __ffs(eqmask) - 1;
            selmask |= 1u << j;
            eqmask &= eqmask - 1u;
        }
    }

    const float inv = 1.0f / S;
    f32x4 o0, o1;
#pragma unroll
    for (int j = 0; j < 8; ++j) {
        const float ej = __expf(x[j] - M) * inv;
        const float oj = ((selmask >> j) & 1u) ? ej : 0.0f;
        if (j < 4) o0[j] = oj; else o1[j - 4] = oj;
    }

    f32x4* q = reinterpret_cast<f32x4*>(out + base);
    __builtin_nontemporal_store(o0, q);
    __builtin_nontemporal_store(o1, q + 1);
}

extern "C" void kernel_launch(void* const* d_in, const int* in_sizes, int n_in,
                              void* d_out, int out_size, void* d_ws, size_t ws_size,
                              hipStream_t stream) {
    const float* in = (const float*)d_in[0];
    float* out = (float*)d_out;
    const int rows = in_sizes[0] / DEPTH;      // 131072
    const int blocks = rows / 4;               // 4 waves (rows) per block
    AnnealingTopKSoftMax_kernel<<<blocks, 256, 0, stream>>>(in, out);
}